// Round 7
// baseline (132.554 us; speedup 1.0000x reference)
//
#include <hip/hip_runtime.h>
#include <hip/hip_fp16.h>
#include <stdint.h>

#define T_LEN 262144
#define S 64
#define SP1 65

// forward: L=32 outputs + W=4 warm-up, ONE chain per wave (TLP > ILP:
// R3 measured 2 chains/wave at SAME wave count ~7us slower; D-bound
// threshold measured +5us twice (R1/R6) -- this is the proven 43.5us form).
#define L_FWD 32
#define W_FWD 4
#define C_FWD (T_LEN / L_FWD)   // 8192
#define C_PER_XCD (C_FWD / 8)   // 1024 chunks per XCD slice

// backtrack: one WAVE per 32-output window, VB3=12 warm chase steps
// (stronger than the proven margin-8). The whole bp column for a t-quad
// is one coalesced 256B load; the chase runs in registers via readlane
// (wave-uniform state -> SALU), eliminating the 491K scattered DEPENDENT
// 4B gathers that bound the old k2 (R0->R1 scaling: time tracks gather
// count, ~25-40cy per unique line through the memory pipe).
#define LB3 32
#define VB3 12
#define NW3 (T_LEN / LB3)       // 8192 windows -> 2048 blocks x 4 waves

// DPP cumulative u32-min step (old = own value, bound_ctrl=false). After
// shr1,2,4,8 + bcast15 + bcast31, lane 63 holds the wave-wide min.
template <int CTRL>
__device__ __forceinline__ unsigned int dpp_umin_step(unsigned int v) {
    unsigned int t = (unsigned int)__builtin_amdgcn_update_dpp(
        (int)v, (int)v, CTRL, 0xf, 0xf, false);
    return min(t, v);
}

__device__ __forceinline__ float readlane_f(float v, int lane) {
    return __int_as_float(__builtin_amdgcn_readlane(__float_as_int(v), lane));
}

// packed argmax key: all scores < 0 -> u32-min on raw bits == float-max;
// low 6 bits carry j, tie-break = first occurrence (smaller j).
__device__ __forceinline__ unsigned int pack_key(float a, int j) {
    return (__float_as_uint(a) & 0xFFFFFFC0u) | (unsigned)j;
}

// k1: chunked forward Viterbi, one chain per wave, 4 chains/block.
// R0/R2-proven form verbatim (43.5us measured twice). Mc column bound,
// packed-key DPP reduce, XCD-swizzled chunk ownership.
__global__ __launch_bounds__(256, 8) void k1_forward(
    const int* __restrict__ rolls, const float* __restrict__ trans,
    const float* __restrict__ ll,
    unsigned int* __restrict__ bp4, int* __restrict__ wsFinal,
    float* __restrict__ out_score) {
    __shared__ __half strans_h[S * S];  // strans_h[j*64 + i] = trans[i][j]
    __shared__ float srowmin[S];
    __shared__ float sMc[S];
    const int tid = threadIdx.x;
    const int lane = tid & 63;
    const int wv = tid >> 6;

    if (blockIdx.x == 0 && tid == 0)
        out_score[0] = 0.0f;  // k2 is stream-ordered after k1 -> safe

    for (int k = tid; k < S * S; k += 256)
        strans_h[k] = __float2half(trans[(k & 63) * SP1 + (k >> 6)]);
    __syncthreads();

    // per-block Mc: rowmin_i = min_j trans[i][j]; Mc[j] = min_i(rowmin_i - trans[i][j])
    {
        int i = tid >> 2, q = tid & 3;
        float mn = 3.0e38f;
        #pragma unroll
        for (int u = 0; u < 16; ++u)
            mn = fminf(mn, __half2float(strans_h[((q * 16 + u) << 6) | i]));
        mn = fminf(mn, __shfl_xor(mn, 1));
        mn = fminf(mn, __shfl_xor(mn, 2));
        if (q == 0) srowmin[i] = mn;
    }
    __syncthreads();
    {
        int j = tid >> 2, q = tid & 3;
        float mc = 3.0e38f;
        #pragma unroll
        for (int u = 0; u < 16; ++u) {
            int i = q * 16 + u;
            mc = fminf(mc, srowmin[i] - __half2float(strans_h[(j << 6) | i]));
        }
        mc = fminf(mc, __shfl_xor(mc, 1));
        mc = fminf(mc, __shfl_xor(mc, 2));
        if (q == 0) sMc[j] = mc;
    }
    __syncthreads();
    const float mcol = sMc[lane];

    // XCD-grouped chunk id: XCD x = g%8 handles chunks x*C_PER_XCD + ...
    const int c = (blockIdx.x & 7) * C_PER_XCD + (blockIdx.x >> 3) * 4 + wv;
    const int beg_out = c * L_FWD;
    int t0 = beg_out - W_FWD;
    if (t0 < 1) t0 = 1;

    // rolls for the whole chunk (plus prefetch slack) in one VGPR
    int vroll = rolls[min(t0 + lane, T_LEN - 1)];

    float delta;
    if (c == 0) {
        delta = trans[lane * SP1 + S] + ll[rolls[0] * S + lane];  // exact init
    } else {
        delta = 0.0f;  // arbitrary; warm-up coalesces (up to additive const)
    }

    // ll pipeline: ll_cur for step t, ll_nxt for t+1; issue t+2 in-loop
    int r0 = __builtin_amdgcn_readlane(vroll, 0);
    int r1 = __builtin_amdgcn_readlane(vroll, 1);
    float ll_cur = ll[r0 * S + lane];
    float ll_nxt = ll[r1 * S + lane];

    int idx = 0;  // t - t0

    auto step = [&]() -> unsigned int {
        int rp = __builtin_amdgcn_readlane(vroll, idx + 2);
        float ll_new = ll[rp * S + lane];  // used at t+2

        float cvec = delta + ll_cur;  // < 0 always

        // one packed u32-min reduce -> wave max value AND its lane id
        unsigned int kv = pack_key(cvec, lane);
        kv = dpp_umin_step<0x111>(kv);
        kv = dpp_umin_step<0x112>(kv);
        kv = dpp_umin_step<0x114>(kv);
        kv = dpp_umin_step<0x118>(kv);
        kv = dpp_umin_step<0x142>(kv);
        kv = dpp_umin_step<0x143>(kv);
        unsigned int kmin =
            (unsigned int)__builtin_amdgcn_readlane((int)kv, 63);

        const int jm = (int)(kmin & 63u);
        // leader column unconditionally; threshold from REGISTER Mc (no
        // jm-dependent LDS read on the ballot's critical path).
        float h0 = __half2float(strans_h[(jm << 6) | lane]);
        float cjm = readlane_f(cvec, jm);
        float thr = __uint_as_float(kmin & 0xFFFFFFC0u) + mcol;
        unsigned int m = pack_key(h0 + cjm, jm);

        unsigned long long mask = __ballot(cvec >= thr) & ~(1ull << jm);
        if (mask) {  // wave-uniform; ~1 extra survivor typical
            int j1 = __ffsll(mask) - 1;
            unsigned long long rm = mask & (mask - 1);
            float a1 = __half2float(strans_h[(j1 << 6) | lane]) +
                       readlane_f(cvec, j1);
            m = min(m, pack_key(a1, j1));
            while (rm) {  // rare (>2 survivors)
                int j = __ffsll(rm) - 1;
                rm &= (rm - 1);
                float a = __half2float(strans_h[(j << 6) | lane]) +
                          readlane_f(cvec, j);
                m = min(m, pack_key(a, j));
            }
        }

        delta = __uint_as_float(m & 0xFFFFFFC0u);  // quantized (~2^-15 rel)
        ll_cur = ll_nxt;
        ll_nxt = ll_new;
        ++idx;
        return m;
    };

    // warm-up: exactly W_FWD steps for c>0 (c==0 starts exact at t=1)
    if (c != 0) {
        #pragma unroll
        for (int w = 0; w < W_FWD; ++w)
            (void)step();
    }

    // main: 8 packed dwords accumulated in registers; burst store at end
    const int qb = beg_out >> 2;
    unsigned int pk[8];
    {   // q = 0: c==0 covers t=1..3 only (byte 0 never read by backtrack)
        unsigned int p = 0u;
        int u0 = (c == 0) ? 1 : 0;
        for (int u = u0; u < 4; ++u) {
            unsigned int m = step();
            p = (p >> 8) | ((m & 63u) << 24);
        }
        pk[0] = p;
    }
    #pragma unroll
    for (int q = 1; q < 8; ++q) {
        unsigned int p = 0u;
        #pragma unroll
        for (int u = 0; u < 4; ++u) {
            unsigned int m = step();
            p = (p >> 8) | ((m & 63u) << 24);
        }
        pk[q] = p;
    }
    #pragma unroll
    for (int q = 0; q < 8; ++q)
        bp4[(unsigned)((qb + q) << 6) | (unsigned)lane] = pk[q];

    if (c == C_FWD - 1) {
        float fmx = delta;
        for (int off = 32; off; off >>= 1)
            fmx = fmaxf(fmx, __shfl_xor(fmx, off));
        unsigned long long em = __ballot(delta == fmx);
        if (lane == 0)
            *wsFinal = __ffsll(em) - 1;
    }
}

// k2: one WAVE per 32-output window. 11 coalesced 256B row loads (whole
// bp column per t-quad; addresses independent -> fully pipelined, zero
// dependent memory), then 43 chase steps IN REGISTERS: s_{t-1} =
// byte(readlane(row, s_t)); s is wave-uniform -> scalar pipe. Path
// captured via one predicated cndmask per step; boundary stitched via
// per-block LDS (own-chase fallback margin 11 > proven 7). Exact fp32
// scoring; one atomic per block. XCD-matched window mapping = k1's.
__global__ __launch_bounds__(256, 8) void k2_backtrack(
    const unsigned int* __restrict__ bp4, const int* __restrict__ wsFinal,
    const int* __restrict__ rolls, const float* __restrict__ trans,
    const float* __restrict__ ll, float* __restrict__ out_path,
    float* __restrict__ out_score) {
    __shared__ int sstlo[4];
    __shared__ float spart[4];
    const int tid = threadIdx.x;
    const int lane = tid & 63;
    const int wv = tid >> 6;
    // same chunk<->block mapping as k1 (window w == forward chunk c)
    const int w = (blockIdx.x & 7) * C_PER_XCD + (blockIdx.x >> 3) * 4 + wv;
    const int tlo = w * LB3;
    const int q0 = tlo >> 2;
    int te = tlo + LB3 + VB3 - 1;   // tlo + 43
    int s;
    if (te >= T_LEN - 1) {
        te = T_LEN - 1;
        s = *wsFinal;   // exact seed: s_{T-1}
    } else {
        s = 0;          // arbitrary; 12-step chase coalesces
    }
    const int dte = te - tlo;       // 43 normally; 31 for the last window

    // 11 independent coalesced row loads (rows beyond bp4 for the last
    // window land in unused ws space: loaded, never consumed)
    unsigned int R0 = bp4[(unsigned)(((q0 + 0) << 6) | lane)];
    unsigned int R1 = bp4[(unsigned)(((q0 + 1) << 6) | lane)];
    unsigned int R2 = bp4[(unsigned)(((q0 + 2) << 6) | lane)];
    unsigned int R3 = bp4[(unsigned)(((q0 + 3) << 6) | lane)];
    unsigned int R4 = bp4[(unsigned)(((q0 + 4) << 6) | lane)];
    unsigned int R5 = bp4[(unsigned)(((q0 + 5) << 6) | lane)];
    unsigned int R6 = bp4[(unsigned)(((q0 + 6) << 6) | lane)];
    unsigned int R7 = bp4[(unsigned)(((q0 + 7) << 6) | lane)];
    unsigned int R8 = bp4[(unsigned)(((q0 + 8) << 6) | lane)];
    unsigned int R9 = bp4[(unsigned)(((q0 + 9) << 6) | lane)];
    unsigned int RA = bp4[(unsigned)(((q0 + 10) << 6) | lane)];

    int cap = 0;  // lane d ends with s_{tlo+d} (d<=31); lane 32 = boundary

    // chase t = tlo+DT, DT = 43..1; before the step s == s_t (capture),
    // after: s == s_{t-1}. Static row names only (no runtime indexing).
#define CHASE(DT, ROW)                                                   \
    do {                                                                 \
        if ((DT) <= dte) {                                               \
            cap = (lane == (DT)) ? s : cap;                              \
            int b_ = __builtin_amdgcn_readlane((int)(ROW), s);           \
            s = (b_ >> (((DT) & 3) << 3)) & 63;                          \
        }                                                                \
    } while (0)

    CHASE(43, RA); CHASE(42, RA); CHASE(41, RA); CHASE(40, RA);
    CHASE(39, R9); CHASE(38, R9); CHASE(37, R9); CHASE(36, R9);
    CHASE(35, R8); CHASE(34, R8); CHASE(33, R8); CHASE(32, R8);
    CHASE(31, R7); CHASE(30, R7); CHASE(29, R7); CHASE(28, R7);
    CHASE(27, R6); CHASE(26, R6); CHASE(25, R6); CHASE(24, R6);
    CHASE(23, R5); CHASE(22, R5); CHASE(21, R5); CHASE(20, R5);
    CHASE(19, R4); CHASE(18, R4); CHASE(17, R4); CHASE(16, R4);
    CHASE(15, R3); CHASE(14, R3); CHASE(13, R3); CHASE(12, R3);
    CHASE(11, R2); CHASE(10, R2); CHASE(9, R2);  CHASE(8, R2);
    CHASE(7, R1);  CHASE(6, R1);  CHASE(5, R1);  CHASE(4, R1);
    CHASE(3, R0);  CHASE(2, R0);  CHASE(1, R0);
#undef CHASE
    cap = (lane == 0) ? s : cap;  // s_{tlo}

    // boundary stitch: wave wv<3 uses neighbor wave's EMITTED s_tlo
    // (windows are consecutive within a block); wv==3 uses own chase at
    // thi+1 (margin 11; last block's boundary term is skipped anyway).
    if (lane == 0) sstlo[wv] = s;
    __syncthreads();
    int bnd = (wv < 3) ? sstlo[wv + 1] : __builtin_amdgcn_readlane(cap, 32);

    // path write: out[T-1-t] = s_t for t in [tlo, tlo+31]
    if (lane < 32)
        out_path[T_LEN - 1 - (tlo + lane)] = (float)cap;

    // score terms: lane k (<32) handles t = tlo+1+k:
    //   trans[s_t][s_{t-1}] + ll[rolls[t]][s_{t-1}]
    int stn = __shfl(cap, lane + 1);
    if (lane == 31) stn = bnd;
    float acc = 0.0f;
    if (lane < 32) {
        int t = tlo + 1 + lane;
        if (t <= T_LEN - 1)
            acc = trans[stn * SP1 + cap] + ll[rolls[t] * S + cap];
        if (w == 0 && lane == 0)  // init term at t=0, state s_0 = cap
            acc += trans[cap * SP1 + S] + ll[rolls[0] * S + cap];
    }

    for (int off = 32; off; off >>= 1)
        acc += __shfl_xor(acc, off);
    if (lane == 0) spart[wv] = acc;
    __syncthreads();
    if (tid == 0)
        atomicAdd(out_score, (spart[0] + spart[1]) + (spart[2] + spart[3]));
}

extern "C" void kernel_launch(void* const* d_in, const int* in_sizes, int n_in,
                              void* d_out, int out_size, void* d_ws, size_t ws_size,
                              hipStream_t stream) {
    const int* rolls = (const int*)d_in[0];
    const float* trans = (const float*)d_in[1];   // (64, 65)
    const float* ll = (const float*)d_in[2];      // (128, 64)
    float* out = (float*)d_out;                   // [0..T): path (reverse), [T]: score
    char* ws = (char*)d_ws;
    int* wsFinal = (int*)(ws + 8);
    unsigned int* bp4 = (unsigned int*)(ws + 2048); // 16 MiB packed bp

    k1_forward<<<C_FWD / 4, 256, 0, stream>>>(rolls, trans, ll, bp4, wsFinal,
                                              out + T_LEN);
    k2_backtrack<<<NW3 / 4, 256, 0, stream>>>(bp4, wsFinal, rolls, trans, ll,
                                              out, out + T_LEN);
}

// Round 8
// 109.189 us; speedup vs baseline: 1.2140x; 1.2140x over previous
//
#include <hip/hip_runtime.h>
#include <hip/hip_fp16.h>
#include <stdint.h>

#define T_LEN 262144
#define S 64
#define SP1 65

// forward: L=32 outputs + W=4 warm-up, ONE chain per wave (TLP > ILP:
// R3 measured 2 chains/wave at half the waves runs 2x slower).
// 8192 chains -> 2048 blocks of 256 -> 8 blocks/CU target residency.
#define L_FWD 32
#define W_FWD 4
#define C_FWD (T_LEN / L_FWD)   // 8192

// backtrack: one THREAD per window. LB=8 outputs, VB=8 warm chase.
// (Ledger: LB=4 -8us; 64-thr blocks -7us; wave-register chase -19us;
//  skip-table 3-kernel -12us. This exact form measured 21.6us.)
#define LB2 8
#define VB2 8
#define NW (T_LEN / LB2)        // 32768 windows -> 128 blocks of 256
#define PITCH (LB2 + 2)

// DPP cumulative-fmax step (old = own value, bound_ctrl=false). After
// shr1,2,4,8 + bcast15 + bcast31, lane 63 holds the wave-wide max.
template <int CTRL>
__device__ __forceinline__ float dpp_fmax_step(float v) {
    int t = __builtin_amdgcn_update_dpp(__float_as_int(v), __float_as_int(v),
                                        CTRL, 0xf, 0xf, false);
    return fmaxf(__int_as_float(t), v);
}

__device__ __forceinline__ float readlane_f(float v, int lane) {
    return __int_as_float(__builtin_amdgcn_readlane(__float_as_int(v), lane));
}

// packed argmax key: all scores < 0 -> u32-min on raw bits == float-max;
// low 6 bits carry j, tie-break = first occurrence (smaller j).
__device__ __forceinline__ unsigned int pack_key(float a, int j) {
    return (__float_as_uint(a) & 0xFFFFFFC0u) | (unsigned)j;
}

// k1: chunked forward Viterbi, one chain per wave, 4 chains/block.
// strans staged as fp16 (8 KB LDS) to test/raise block residency per CU.
// Per-block Mc (column-min pruning bound, computed from the SAME fp16
// trans the update uses -> bound stays exact for the computation done):
// Mc[j] = min_i(rowmin_i - trans[i][j]) <= 0; winner j of any row
// satisfies c_j >= cmax + Mc[j]. Loads-only steady-state vmcnt queue;
// bp bytes packed 4/dword in registers, burst-stored at chunk end.
// NOTE (R1/R6): replacing Mc with the tighter D[jm][j] bound REGRESSES
// ~5us -- the jm-dependent LDS read lands on the ballot's critical path.
// NOTE (R6 paradox): survivor count is NOT the binding cost; do not
// re-attempt survivor pruning without new per-kernel counter evidence.
__global__ __launch_bounds__(256, 8) void k1_forward(
    const int* __restrict__ rolls, const float* __restrict__ trans,
    const float* __restrict__ ll,
    unsigned int* __restrict__ bp4, int* __restrict__ wsFinal,
    float* __restrict__ out_score) {
    __shared__ __half strans_h[S * S];  // strans_h[j*64 + i] = trans[i][j]
    __shared__ float srowmin[S];
    __shared__ float sMc[S];
    const int tid = threadIdx.x;
    const int lane = tid & 63;
    const int wv = tid >> 6;

    if (blockIdx.x == 0 && tid == 0)
        out_score[0] = 0.0f;  // k2 is stream-ordered after k1 -> safe

    for (int k = tid; k < S * S; k += 256)
        strans_h[k] = __float2half(trans[(k & 63) * SP1 + (k >> 6)]);
    __syncthreads();

    // per-block Mc: rowmin_i = min_j trans[i][j]; Mc[j] = min_i(rowmin_i - trans[i][j])
    {
        int i = tid >> 2, q = tid & 3;
        float mn = 3.0e38f;
        #pragma unroll
        for (int u = 0; u < 16; ++u)
            mn = fminf(mn, __half2float(strans_h[((q * 16 + u) << 6) | i]));
        mn = fminf(mn, __shfl_xor(mn, 1));
        mn = fminf(mn, __shfl_xor(mn, 2));
        if (q == 0) srowmin[i] = mn;
    }
    __syncthreads();
    {
        int j = tid >> 2, q = tid & 3;
        float mc = 3.0e38f;
        #pragma unroll
        for (int u = 0; u < 16; ++u) {
            int i = q * 16 + u;
            mc = fminf(mc, srowmin[i] - __half2float(strans_h[(j << 6) | i]));
        }
        mc = fminf(mc, __shfl_xor(mc, 1));
        mc = fminf(mc, __shfl_xor(mc, 2));
        if (q == 0) sMc[j] = mc;
    }
    __syncthreads();
    const float mcol = sMc[lane];

    const int c = blockIdx.x * 4 + wv;
    const int beg_out = c * L_FWD;
    int t0 = beg_out - W_FWD;
    if (t0 < 1) t0 = 1;

    // rolls for the whole chunk (plus prefetch slack) in one VGPR
    int vroll = rolls[min(t0 + lane, T_LEN - 1)];

    float delta;
    if (c == 0) {
        delta = trans[lane * SP1 + S] + ll[rolls[0] * S + lane];  // exact init
    } else {
        delta = 0.0f;  // arbitrary; warm-up coalesces (up to additive const)
    }

    // ll pipeline: ll_cur for step t, ll_nxt for t+1; issue t+2 in-loop
    int r0 = __builtin_amdgcn_readlane(vroll, 0);
    int r1 = __builtin_amdgcn_readlane(vroll, 1);
    float ll_cur = ll[r0 * S + lane];
    float ll_nxt = ll[r1 * S + lane];

    int idx = 0;  // t - t0

    auto step = [&]() -> unsigned int {
        int rp = __builtin_amdgcn_readlane(vroll, idx + 2);
        float ll_new = ll[rp * S + lane];  // used at t+2

        float cvec = delta + ll_cur;  // < 0 always

        // exact wave-wide max via fused dpp fmax chain
        float mxc = cvec;
        mxc = dpp_fmax_step<0x111>(mxc);
        mxc = dpp_fmax_step<0x112>(mxc);
        mxc = dpp_fmax_step<0x114>(mxc);
        mxc = dpp_fmax_step<0x118>(mxc);
        mxc = dpp_fmax_step<0x142>(mxc);
        mxc = dpp_fmax_step<0x143>(mxc);
        float cmax = readlane_f(mxc, 63);

        // exact per-lane pruning: survivors satisfy c_j >= cmax + Mc[j];
        // argmax lane always present (Mc <= 0)
        float thr = cmax + mcol;
        unsigned long long mask = __ballot(cvec >= thr);

        int j0 = __ffsll(mask) - 1;
        unsigned long long rm = mask & (mask - 1);
        int j1 = rm ? (__ffsll(rm) - 1) : j0;
        float a0 = __half2float(strans_h[(j0 << 6) | lane]) + readlane_f(cvec, j0);
        float a1 = __half2float(strans_h[(j1 << 6) | lane]) + readlane_f(cvec, j1);
        unsigned int m = min(pack_key(a0, j0), pack_key(a1, j1));

        unsigned long long rest = rm ? (rm & (rm - 1)) : 0ull;
        if (rest) {  // wave-uniform scalar branch; ~1/3 of steps
            int j2 = __ffsll(rest) - 1;
            unsigned long long r3 = rest & (rest - 1);
            int j3 = r3 ? (__ffsll(r3) - 1) : j2;
            float a2 = __half2float(strans_h[(j2 << 6) | lane]) + readlane_f(cvec, j2);
            float a3 = __half2float(strans_h[(j3 << 6) | lane]) + readlane_f(cvec, j3);
            m = min(m, min(pack_key(a2, j2), pack_key(a3, j3)));
            rest = r3 ? (r3 & (r3 - 1)) : 0ull;
            while (rest) {  // rare (>4 survivors)
                int j = __ffsll(rest) - 1;
                rest &= (rest - 1);
                float a = __half2float(strans_h[(j << 6) | lane]) + readlane_f(cvec, j);
                m = min(m, pack_key(a, j));
            }
        }

        delta = __uint_as_float(m & 0xFFFFFFC0u);  // quantized (~2^-15 rel)
        ll_cur = ll_nxt;
        ll_nxt = ll_new;
        ++idx;
        return m;
    };

    // warm-up: exactly W_FWD steps for c>0 (c==0 starts exact at t=1)
    if (c != 0) {
        #pragma unroll
        for (int w = 0; w < W_FWD; ++w)
            (void)step();
    }

    // main: 8 packed dwords accumulated in registers; burst store at end
    const int qb = beg_out >> 2;
    unsigned int pk[8];
    {   // q = 0: c==0 covers t=1..3 only (byte 0 never read by backtrack)
        unsigned int p = 0u;
        int u0 = (c == 0) ? 1 : 0;
        for (int u = u0; u < 4; ++u) {
            unsigned int m = step();
            p = (p >> 8) | ((m & 63u) << 24);
        }
        pk[0] = p;
    }
    #pragma unroll
    for (int q = 1; q < 8; ++q) {
        unsigned int p = 0u;
        #pragma unroll
        for (int u = 0; u < 4; ++u) {
            unsigned int m = step();
            p = (p >> 8) | ((m & 63u) << 24);
        }
        pk[q] = p;
    }
    #pragma unroll
    for (int q = 0; q < 8; ++q)
        bp4[(unsigned)((qb + q) << 6) | (unsigned)lane] = pk[q];

    if (c == C_FWD - 1) {
        float fmx = delta;
        for (int off = 32; off; off >>= 1)
            fmx = fmaxf(fmx, __shfl_xor(fmx, off));
        unsigned long long em = __ballot(delta == fmx);
        if (lane == 0)
            *wsFinal = __ffsll(em) - 1;
    }
}

// k2: one THREAD per window. Chase 15 dependent gathers from te=thi+VB2
// (single seed; bp columns concentrate on ~2 survivors so backward chains
// coalesce inside VB2=8), record s[tlo..thi+1] in LDS, write the path,
// then score own window with neighbor-stitched boundary; one atomic/block.
// Scoring uses fp32 tables -> returned score is exact for the emitted path.
// NOTE (ledger): every attempted restructure of this kernel regressed;
// its cost is NOT explained by gather-count, latency-chain, or occupancy
// models alone -- do not touch without per-kernel counters.
__global__ __launch_bounds__(256) void k2_backtrack(
    const unsigned int* __restrict__ bp4, const int* __restrict__ wsFinal,
    const int* __restrict__ rolls, const float* __restrict__ trans,
    const float* __restrict__ ll, float* __restrict__ out_path,
    float* __restrict__ out_score) {
    __shared__ int sst[256 * PITCH];
    __shared__ float spart[4];
    const int tid = threadIdx.x;
    const int b = blockIdx.x * 256 + tid;   // window id
    const int tlo = b * LB2;
    const int thi = tlo + LB2 - 1;
    int te = thi + VB2;
    int s;
    if (te >= T_LEN - 1) {
        te = T_LEN - 1;
        s = *wsFinal;   // exact seed for the tail windows
    } else {
        s = 0;          // arbitrary; chase coalesces
    }
    int* row = sst + tid * PITCH;
    #pragma unroll
    for (int u = 0; u < LB2 + VB2 - 1; ++u) {  // 15 dependent gathers max
        int t = te - u;
        if (t > tlo) {
            if (t <= thi + 1) row[t - tlo] = s;
            unsigned int w = bp4[((unsigned)(t >> 2) << 6) | (unsigned)s];
            s = (int)((w >> ((t & 3) << 3)) & 63u);
        }
    }
    row[0] = s;  // state at tlo
    __syncthreads();

    // path write: out[T-1-t] = s_t for t in [tlo, thi]
    #pragma unroll
    for (int u = 0; u < LB2; ++u)
        out_path[T_LEN - 1 - (tlo + u)] = (float)row[u];

    // score terms: t in [tlo+1, thi+1] (clamped to T-1):
    //   trans[s_t][s_{t-1}] + ll[rolls[t]][s_{t-1}]
    // boundary s_{thi+1}: neighbor thread's row[0] (the state actually
    // emitted); tid==255 uses own chase state at thi+1.
    float acc = 0.0f;
    #pragma unroll
    for (int u = 1; u <= LB2; ++u) {
        int t = tlo + u;
        if (t <= T_LEN - 1) {
            int sp = row[u - 1];
            int st = (u == LB2)
                         ? ((tid < 255) ? sst[(tid + 1) * PITCH] : row[LB2])
                         : row[u];
            acc += trans[st * SP1 + sp] + ll[rolls[t] * S + sp];
        }
    }
    if (b == 0) {  // init term
        int s0 = row[0];
        acc += trans[s0 * SP1 + S] + ll[rolls[0] * S + s0];
    }

    for (int off = 32; off; off >>= 1)
        acc += __shfl_xor(acc, off);
    if ((tid & 63) == 0) spart[tid >> 6] = acc;
    __syncthreads();
    if (tid == 0)
        atomicAdd(out_score, (spart[0] + spart[1]) + (spart[2] + spart[3]));
}

extern "C" void kernel_launch(void* const* d_in, const int* in_sizes, int n_in,
                              void* d_out, int out_size, void* d_ws, size_t ws_size,
                              hipStream_t stream) {
    const int* rolls = (const int*)d_in[0];
    const float* trans = (const float*)d_in[1];   // (64, 65)
    const float* ll = (const float*)d_in[2];      // (128, 64)
    float* out = (float*)d_out;                   // [0..T): path (reverse), [T]: score
    char* ws = (char*)d_ws;
    int* wsFinal = (int*)(ws + 8);
    unsigned int* bp4 = (unsigned int*)(ws + 2048); // 16 MiB packed bp

    k1_forward<<<C_FWD / 4, 256, 0, stream>>>(rolls, trans, ll, bp4, wsFinal,
                                              out + T_LEN);
    k2_backtrack<<<NW / 256, 256, 0, stream>>>(bp4, wsFinal, rolls, trans, ll,
                                               out, out + T_LEN);
}